// Round 1
// baseline (172.946 us; speedup 1.0000x reference)
//
#include <hip/hip_runtime.h>
#include <hip/hip_fp16.h>

// ---------------------------------------------------------------------------
// DoubleAttention (A^2-Net) on MI355X.
// B=16, C=512, N=4096 (64x64), cm=cn=128.
// Pipeline:
//   prep:  W* -> fp16, x -> xT[b][n][c] fp16 (transpose so every GEMM operand
//          is [rows][contraction-contiguous])
//   gemm_abv: A = WA@x+bA (fp16 out), Bm = softmax(WB@x+bB) [k][n],
//             VmT = softmax(WV@x+bV) stored transposed [n][k]
//             (softmax over 128 channels fused in epilogue via shfl+LDS)
//   gd:    gd[m][k] = sum_n A[m][n]*Bm[k][n]   (K-split 16 + fp32 atomicAdd)
//   z:     ZT[n][m] = sum_k gd[m][k]*VmT[n][k] (stored transposed)
//   out:   out[c][n] = sum_m WR[c][m]*ZT[n][m] + bR[c]  (fp32 out)
// All MFMA: v_mfma_f32_16x16x32_f16, fp32 accumulate.
// ---------------------------------------------------------------------------

typedef _Float16 half8 __attribute__((ext_vector_type(8)));
typedef float f32x4 __attribute__((ext_vector_type(4)));

__device__ __forceinline__ unsigned short f2h(float v) {
  return __builtin_bit_cast(unsigned short, (_Float16)v);
}

__device__ __forceinline__ f32x4 mfma16(half8 a, half8 b, f32x4 c) {
  return __builtin_amdgcn_mfma_f32_16x16x32_f16(a, b, c, 0, 0, 0);
}

// Stage a [128 rows][32 k] fp16 tile from k-contiguous global memory into
// frag-contiguous LDS: 16B block per (kg,row) at ushort index (kg*128+row)*8,
// holding k = 4*kg + j (bytes 0..7) and k = 16 + 4*kg + j (bytes 8..15).
// A fragment read is then a single 16B load per lane (conflict-free:
// 64 lanes spread evenly over 8 bank-quads).
__device__ __forceinline__ void stage_tile(unsigned short* lds,
                                           const unsigned short* g,
                                           int gs, int k0) {
  const int tid = threadIdx.x;
#pragma unroll
  for (int i = 0; i < 2; ++i) {
    int c = tid + 256 * i;          // 0..511 chunks of 8 fp16
    int row = c >> 2, q = c & 3;    // 4 chunks per row
    uint4 v = *(const uint4*)&g[(size_t)row * gs + k0 + q * 8];
    int kgA = (q & 1) * 2, h = q >> 1;
    *(uint2*)&lds[(kgA * 128 + row) * 8 + h * 4]       = make_uint2(v.x, v.y);
    *(uint2*)&lds[((kgA + 1) * 128 + row) * 8 + h * 4] = make_uint2(v.z, v.w);
  }
}

__device__ __forceinline__ half8 ld_frag(const unsigned short* lds, int row) {
  int kg = (threadIdx.x & 63) >> 4;
  uint4 u = *(const uint4*)&lds[(kg * 128 + row) * 8];
  return __builtin_bit_cast(half8, u);
}

// ---------------------------------------------------------------------------
__global__ __launch_bounds__(256) void k_prep_w(
    const float* __restrict__ WA, const float* __restrict__ WB,
    const float* __restrict__ WV, const float* __restrict__ WR,
    unsigned short* __restrict__ Wh, unsigned short* __restrict__ WRh) {
  int idx = blockIdx.x * 256 + threadIdx.x;   // 0..262143
  if (idx < 196608) {
    int mg = idx >> 16, r = idx & 65535;
    const float* src = (mg == 0) ? WA : ((mg == 1) ? WB : WV);
    Wh[idx] = f2h(src[r]);
  } else {
    int r = idx - 196608;
    WRh[r] = f2h(WR[r]);
  }
}

// x[b][c][n] fp32 -> xT[b][n][c] fp16, 32x32 tiles through LDS
__global__ __launch_bounds__(256) void k_transpose_x(
    const float* __restrict__ x, unsigned short* __restrict__ xT) {
  const int n0 = blockIdx.x * 32, c0 = blockIdx.y * 32, b = blockIdx.z;
  __shared__ unsigned short sT[32][33];
  const int t = threadIdx.x;
  {
    int cr = t >> 3, nc = (t & 7) * 4;
    float4 v = *(const float4*)&x[((size_t)b * 512 + c0 + cr) * 4096 + n0 + nc];
    sT[cr][nc + 0] = f2h(v.x);
    sT[cr][nc + 1] = f2h(v.y);
    sT[cr][nc + 2] = f2h(v.z);
    sT[cr][nc + 3] = f2h(v.w);
  }
  __syncthreads();
  {
    int nr = t >> 3, cc = (t & 7) * 4;
    ushort4 o;
    o.x = sT[cc + 0][nr]; o.y = sT[cc + 1][nr];
    o.z = sT[cc + 2][nr]; o.w = sT[cc + 3][nr];
    *(ushort4*)&xT[((size_t)b * 4096 + n0 + nr) * 512 + c0 + cc] = o;
  }
}

// ---------------------------------------------------------------------------
// ABV GEMM + fused channel-softmax epilogue.
// grid (32 n-tiles, 3 m-groups, 16 batch), 256 threads (4 waves, 2x2).
__global__ __launch_bounds__(256) void k_gemm_abv(
    const unsigned short* __restrict__ xT, const unsigned short* __restrict__ Wh,
    const float* __restrict__ bA, const float* __restrict__ bB,
    const float* __restrict__ bV,
    unsigned short* __restrict__ Aout, unsigned short* __restrict__ Bmout,
    unsigned short* __restrict__ VmTout) {
  const int nt = blockIdx.x, mg = blockIdx.y, b = blockIdx.z;
  const int tid = threadIdx.x, lane = tid & 63;
  const int w = tid >> 6, wr = w >> 1, wc = w & 1;
  const int kg = lane >> 4, lidx = lane & 15;

  __shared__ unsigned short sW[4096], sX[4096];
  __shared__ float colmax[2][128], colsum[2][128], sBias[128];

  const float* bias = (mg == 0) ? bA : ((mg == 1) ? bB : bV);
  if (tid < 128) sBias[tid] = bias[tid];

  const unsigned short* Wg = Wh + (size_t)mg * 128 * 512;
  const unsigned short* Xg = xT + ((size_t)b * 4096 + (size_t)nt * 128) * 512;

  f32x4 acc[4][4];
#pragma unroll
  for (int mf = 0; mf < 4; ++mf)
#pragma unroll
    for (int nf = 0; nf < 4; ++nf) acc[mf][nf] = (f32x4){0.f, 0.f, 0.f, 0.f};

  for (int k0 = 0; k0 < 512; k0 += 32) {
    stage_tile(sW, Wg, 512, k0);
    stage_tile(sX, Xg, 512, k0);
    __syncthreads();
    half8 af[4];
#pragma unroll
    for (int mf = 0; mf < 4; ++mf) af[mf] = ld_frag(sW, wr * 64 + mf * 16 + lidx);
#pragma unroll
    for (int nf = 0; nf < 4; ++nf) {
      half8 bf = ld_frag(sX, wc * 64 + nf * 16 + lidx);
#pragma unroll
      for (int mf = 0; mf < 4; ++mf) acc[mf][nf] = mfma16(af[mf], bf, acc[mf][nf]);
    }
    __syncthreads();
  }

  // bias (rows m = wr*64 + mf*16 + kg*4 + i)
#pragma unroll
  for (int mf = 0; mf < 4; ++mf)
#pragma unroll
    for (int i = 0; i < 4; ++i) {
      float bb = sBias[wr * 64 + mf * 16 + kg * 4 + i];
#pragma unroll
      for (int nf = 0; nf < 4; ++nf) acc[mf][nf][i] += bb;
    }

  const size_t bofs = (size_t)b * 128 * 4096;
  if (mg == 0) {  // A: no softmax
#pragma unroll
    for (int mf = 0; mf < 4; ++mf)
#pragma unroll
      for (int nf = 0; nf < 4; ++nf)
#pragma unroll
        for (int i = 0; i < 4; ++i) {
          int m_ = wr * 64 + mf * 16 + kg * 4 + i;
          int n_ = nt * 128 + wc * 64 + nf * 16 + lidx;
          Aout[bofs + (size_t)m_ * 4096 + n_] = f2h(acc[mf][nf][i]);
        }
    return;
  }

  // softmax over the 128 m-rows for each column n
  float cmax[4], csum[4];
#pragma unroll
  for (int nf = 0; nf < 4; ++nf) {
    float m = -1e30f;
#pragma unroll
    for (int mf = 0; mf < 4; ++mf)
#pragma unroll
      for (int i = 0; i < 4; ++i) m = fmaxf(m, acc[mf][nf][i]);
    m = fmaxf(m, __shfl_xor(m, 16));
    m = fmaxf(m, __shfl_xor(m, 32));
    cmax[nf] = m;
  }
  if (kg == 0) {
#pragma unroll
    for (int nf = 0; nf < 4; ++nf) colmax[wr][wc * 64 + nf * 16 + lidx] = cmax[nf];
  }
  __syncthreads();
#pragma unroll
  for (int nf = 0; nf < 4; ++nf)
    cmax[nf] = fmaxf(cmax[nf], colmax[wr ^ 1][wc * 64 + nf * 16 + lidx]);
#pragma unroll
  for (int nf = 0; nf < 4; ++nf) {
    float s = 0.f;
#pragma unroll
    for (int mf = 0; mf < 4; ++mf)
#pragma unroll
      for (int i = 0; i < 4; ++i) {
        float e = __expf(acc[mf][nf][i] - cmax[nf]);
        acc[mf][nf][i] = e;
        s += e;
      }
    s += __shfl_xor(s, 16);
    s += __shfl_xor(s, 32);
    csum[nf] = s;
  }
  if (kg == 0) {
#pragma unroll
    for (int nf = 0; nf < 4; ++nf) colsum[wr][wc * 64 + nf * 16 + lidx] = csum[nf];
  }
  __syncthreads();
  float inv_s[4];
#pragma unroll
  for (int nf = 0; nf < 4; ++nf)
    inv_s[nf] = 1.f / (csum[nf] + colsum[wr ^ 1][wc * 64 + nf * 16 + lidx]);

  if (mg == 1) {  // Bm[b][k][n]
#pragma unroll
    for (int mf = 0; mf < 4; ++mf)
#pragma unroll
      for (int nf = 0; nf < 4; ++nf)
#pragma unroll
        for (int i = 0; i < 4; ++i) {
          int m_ = wr * 64 + mf * 16 + kg * 4 + i;
          int n_ = nt * 128 + wc * 64 + nf * 16 + lidx;
          Bmout[bofs + (size_t)m_ * 4096 + n_] = f2h(acc[mf][nf][i] * inv_s[nf]);
        }
  } else {        // VmT[b][n][k]  (transposed, 4 rows packed per store)
    const size_t vofs = (size_t)b * 4096 * 128;
#pragma unroll
    for (int mf = 0; mf < 4; ++mf)
#pragma unroll
      for (int nf = 0; nf < 4; ++nf) {
        int m0 = wr * 64 + mf * 16 + kg * 4;
        int n_ = nt * 128 + wc * 64 + nf * 16 + lidx;
        ushort4 pk;
        pk.x = f2h(acc[mf][nf][0] * inv_s[nf]);
        pk.y = f2h(acc[mf][nf][1] * inv_s[nf]);
        pk.z = f2h(acc[mf][nf][2] * inv_s[nf]);
        pk.w = f2h(acc[mf][nf][3] * inv_s[nf]);
        *(ushort4*)&VmTout[vofs + (size_t)n_ * 128 + m0] = pk;
      }
  }
}

// ---------------------------------------------------------------------------
// gd[b][m][k] = sum_n A[b][m][n]*Bm[b][k][n]; grid (16 k-splits, 16 batch)
__global__ __launch_bounds__(256) void k_gd(
    const unsigned short* __restrict__ A, const unsigned short* __restrict__ Bm,
    float* __restrict__ gd) {
  const int ks = blockIdx.x, b = blockIdx.y;
  const int tid = threadIdx.x, lane = tid & 63;
  const int w = tid >> 6, wr = w >> 1, wc = w & 1;
  const int kg = lane >> 4, lidx = lane & 15;
  __shared__ unsigned short sA[4096], sB[4096];
  const unsigned short* Ab = A + (size_t)b * 128 * 4096 + (size_t)ks * 256;
  const unsigned short* Bb = Bm + (size_t)b * 128 * 4096 + (size_t)ks * 256;

  f32x4 acc[4][4];
#pragma unroll
  for (int mf = 0; mf < 4; ++mf)
#pragma unroll
    for (int nf = 0; nf < 4; ++nf) acc[mf][nf] = (f32x4){0.f, 0.f, 0.f, 0.f};

  for (int k0 = 0; k0 < 256; k0 += 32) {
    stage_tile(sA, Ab, 4096, k0);
    stage_tile(sB, Bb, 4096, k0);
    __syncthreads();
    half8 af[4];
#pragma unroll
    for (int mf = 0; mf < 4; ++mf) af[mf] = ld_frag(sA, wr * 64 + mf * 16 + lidx);
#pragma unroll
    for (int nf = 0; nf < 4; ++nf) {
      half8 bf = ld_frag(sB, wc * 64 + nf * 16 + lidx);
#pragma unroll
      for (int mf = 0; mf < 4; ++mf) acc[mf][nf] = mfma16(af[mf], bf, acc[mf][nf]);
    }
    __syncthreads();
  }
  float* gb = gd + (size_t)b * 128 * 128;
#pragma unroll
  for (int mf = 0; mf < 4; ++mf)
#pragma unroll
    for (int nf = 0; nf < 4; ++nf)
#pragma unroll
      for (int i = 0; i < 4; ++i) {
        int m_ = wr * 64 + mf * 16 + kg * 4 + i;
        int k2 = wc * 64 + nf * 16 + lidx;
        atomicAdd(&gb[(size_t)m_ * 128 + k2], acc[mf][nf][i]);
      }
}

// ---------------------------------------------------------------------------
// ZT[b][n][m] = sum_k gd[b][m][k]*VmT[b][n][k]; grid (32 n-tiles, 16 batch)
__global__ __launch_bounds__(256) void k_z(
    const float* __restrict__ gd, const unsigned short* __restrict__ VmT,
    unsigned short* __restrict__ ZT) {
  const int nt = blockIdx.x, b = blockIdx.y;
  const int tid = threadIdx.x, lane = tid & 63;
  const int w = tid >> 6, wr = w >> 1, wc = w & 1;
  const int kg = lane >> 4, lidx = lane & 15;
  __shared__ unsigned short sG[4096], sV[4096];
  const float4* gb = (const float4*)(gd + (size_t)b * 128 * 128);
  const unsigned short* Vb = VmT + ((size_t)b * 4096 + (size_t)nt * 128) * 128;

  f32x4 acc[4][4];
#pragma unroll
  for (int mf = 0; mf < 4; ++mf)
#pragma unroll
    for (int nf = 0; nf < 4; ++nf) acc[mf][nf] = (f32x4){0.f, 0.f, 0.f, 0.f};

  for (int k0 = 0; k0 < 128; k0 += 32) {
    // stage gd tile with fp32->fp16 conversion
#pragma unroll
    for (int i = 0; i < 4; ++i) {
      int c = tid + 256 * i;          // 0..1023
      int row = c >> 3, q8 = c & 7;   // 8 float4-chunks per row window
      float4 v = gb[row * 32 + (k0 >> 2) + q8];
      unsigned int lo = (unsigned)f2h(v.x) | ((unsigned)f2h(v.y) << 16);
      unsigned int hi = (unsigned)f2h(v.z) | ((unsigned)f2h(v.w) << 16);
      int kgq = q8 & 3, h = q8 >> 2;
      *(uint2*)&sG[(kgq * 128 + row) * 8 + h * 4] = make_uint2(lo, hi);
    }
    stage_tile(sV, Vb, 128, k0);
    __syncthreads();
    half8 af[4];
#pragma unroll
    for (int mf = 0; mf < 4; ++mf) af[mf] = ld_frag(sG, wr * 64 + mf * 16 + lidx);
#pragma unroll
    for (int nf = 0; nf < 4; ++nf) {
      half8 bf = ld_frag(sV, wc * 64 + nf * 16 + lidx);
#pragma unroll
      for (int mf = 0; mf < 4; ++mf) acc[mf][nf] = mfma16(af[mf], bf, acc[mf][nf]);
    }
    __syncthreads();
  }
  const size_t zofs = (size_t)b * 4096 * 128;
#pragma unroll
  for (int mf = 0; mf < 4; ++mf)
#pragma unroll
    for (int nf = 0; nf < 4; ++nf) {
      int m0 = wr * 64 + mf * 16 + kg * 4;
      int n_ = nt * 128 + wc * 64 + nf * 16 + lidx;
      ushort4 pk;
      pk.x = f2h(acc[mf][nf][0]);
      pk.y = f2h(acc[mf][nf][1]);
      pk.z = f2h(acc[mf][nf][2]);
      pk.w = f2h(acc[mf][nf][3]);
      *(ushort4*)&ZT[zofs + (size_t)n_ * 128 + m0] = pk;
    }
}

// ---------------------------------------------------------------------------
// out[b][c][n] = sum_m WR[c][m]*ZT[b][n][m] + bR[c]; grid (32 nt, 4 ct, 16 b)
__global__ __launch_bounds__(256) void k_out(
    const unsigned short* __restrict__ WRh, const unsigned short* __restrict__ ZT,
    const float* __restrict__ bR, float* __restrict__ out) {
  const int nt = blockIdx.x, ct = blockIdx.y, b = blockIdx.z;
  const int tid = threadIdx.x, lane = tid & 63;
  const int w = tid >> 6, wr = w >> 1, wc = w & 1;
  const int kg = lane >> 4, lidx = lane & 15;
  __shared__ unsigned short sW[4096], sZ[4096];
  __shared__ float sBias[128];
  if (tid < 128) sBias[tid] = bR[ct * 128 + tid];
  const unsigned short* Wb = WRh + (size_t)ct * 128 * 128;
  const unsigned short* Zb = ZT + ((size_t)b * 4096 + (size_t)nt * 128) * 128;

  f32x4 acc[4][4];
#pragma unroll
  for (int mf = 0; mf < 4; ++mf)
#pragma unroll
    for (int nf = 0; nf < 4; ++nf) acc[mf][nf] = (f32x4){0.f, 0.f, 0.f, 0.f};

  for (int k0 = 0; k0 < 128; k0 += 32) {
    stage_tile(sW, Wb, 128, k0);
    stage_tile(sZ, Zb, 128, k0);
    __syncthreads();
    half8 af[4];
#pragma unroll
    for (int mf = 0; mf < 4; ++mf) af[mf] = ld_frag(sW, wr * 64 + mf * 16 + lidx);
#pragma unroll
    for (int nf = 0; nf < 4; ++nf) {
      half8 bf = ld_frag(sZ, wc * 64 + nf * 16 + lidx);
#pragma unroll
      for (int mf = 0; mf < 4; ++mf) acc[mf][nf] = mfma16(af[mf], bf, acc[mf][nf]);
    }
    __syncthreads();
  }
#pragma unroll
  for (int mf = 0; mf < 4; ++mf)
#pragma unroll
    for (int nf = 0; nf < 4; ++nf)
#pragma unroll
      for (int i = 0; i < 4; ++i) {
        int cl = wr * 64 + mf * 16 + kg * 4 + i;
        int n_ = nt * 128 + wc * 64 + nf * 16 + lidx;
        out[((size_t)b * 512 + ct * 128 + cl) * 4096 + n_] = acc[mf][nf][i] + sBias[cl];
      }
}

// ---------------------------------------------------------------------------
extern "C" void kernel_launch(void* const* d_in, const int* in_sizes, int n_in,
                              void* d_out, int out_size, void* d_ws, size_t ws_size,
                              hipStream_t stream) {
  const float* x  = (const float*)d_in[0];
  const float* WA = (const float*)d_in[1];
  const float* bA = (const float*)d_in[2];
  const float* WB = (const float*)d_in[3];
  const float* bB = (const float*)d_in[4];
  const float* WV = (const float*)d_in[5];
  const float* bV = (const float*)d_in[6];
  const float* WR = (const float*)d_in[7];
  const float* bR = (const float*)d_in[8];
  float* out = (float*)d_out;

  char* ws = (char*)d_ws;
  unsigned short* Wh   = (unsigned short*)(ws);               // 3*128*512 fp16
  unsigned short* WRh  = (unsigned short*)(ws + 393216);      // 512*128 fp16
  unsigned short* xT   = (unsigned short*)(ws + 524288);      // 16*4096*512 fp16
  unsigned short* Aout = (unsigned short*)(ws + 67633152);    // 16*128*4096 fp16
  unsigned short* Bm   = (unsigned short*)(ws + 84410368);    // 16*128*4096 fp16
  unsigned short* VmT  = (unsigned short*)(ws + 101187584);   // 16*4096*128 fp16
  float*          gd   = (float*)(ws + 117964800);            // 16*128*128 fp32
  unsigned short* ZT   = (unsigned short*)(ws + 119013376);   // 16*4096*128 fp16

  hipMemsetAsync(gd, 0, (size_t)16 * 128 * 128 * sizeof(float), stream);
  k_prep_w<<<1024, 256, 0, stream>>>(WA, WB, WV, WR, Wh, WRh);
  k_transpose_x<<<dim3(128, 16, 16), 256, 0, stream>>>(x, xT);
  k_gemm_abv<<<dim3(32, 3, 16), 256, 0, stream>>>(xT, Wh, bA, bB, bV, Aout, Bm, VmT);
  k_gd<<<dim3(16, 16), 256, 0, stream>>>(Aout, Bm, gd);
  k_z<<<dim3(32, 16), 256, 0, stream>>>(gd, VmT, ZT);
  k_out<<<dim3(32, 4, 16), 256, 0, stream>>>(WRh, ZT, bR, out);
}